// Round 2
// baseline (470.183 us; speedup 1.0000x reference)
//
#include <hip/hip_runtime.h>

typedef __bf16 bf16;
typedef __bf16 bf16x4_t __attribute__((ext_vector_type(4)));
typedef __bf16 bf16x8_t __attribute__((ext_vector_type(8)));
typedef float  f32x4_t  __attribute__((ext_vector_type(4)));
typedef unsigned int u32x4_t __attribute__((ext_vector_type(4)));

#define S_LEN 2048
#define NHEAD 16
#define NBH   64   // B*H

// async global->LDS, 16B per lane, linear dest (wave-uniform base + lane*16)
static __device__ __forceinline__ void glds16(const void* g, void* l) {
  __builtin_amdgcn_global_load_lds(
      (const __attribute__((address_space(1))) unsigned int*)g,
      (__attribute__((address_space(3))) unsigned int*)l, 16, 0, 0);
}

static __device__ __forceinline__ unsigned pk2(float lo, float hi) {
  unsigned short a = __builtin_bit_cast(unsigned short, (bf16)lo);
  unsigned short b = __builtin_bit_cast(unsigned short, (bf16)hi);
  return (unsigned)a | ((unsigned)b << 16);
}

// ---------------- f32 -> bf16 converts ----------------
__global__ __launch_bounds__(256) void cvt_x_kernel(const float4* __restrict__ in,
                                                    bf16x4_t* __restrict__ out) {
  int i = blockIdx.x * 256 + threadIdx.x;   // exactly 2097152 threads
  float4 v = in[i];
  bf16x4_t o = { (bf16)v.x, (bf16)v.y, (bf16)v.z, (bf16)v.w };
  out[i] = o;
}

__global__ __launch_bounds__(256) void cvt_w_kernel(const float* __restrict__ w0, const float* __restrict__ w1,
                                                    const float* __restrict__ w2, const float* __restrict__ w3,
                                                    bf16x4_t* __restrict__ out) {
  int i = blockIdx.x * 256 + threadIdx.x;   // exactly 1048576 threads (4 x 262144 float4)
  int sel = i >> 18;
  int j = i & 262143;
  const float4* src = (const float4*)(sel == 0 ? w0 : sel == 1 ? w1 : sel == 2 ? w2 : w3);
  float4 v = src[j];
  bf16x4_t o = { (bf16)v.x, (bf16)v.y, (bf16)v.z, (bf16)v.w };
  out[i] = o;
}

// ---------------- RoPE (in-place on q_ws, k_ws) ----------------
__global__ __launch_bounds__(256) void rope_kernel(bf16* __restrict__ q, bf16* __restrict__ k) {
  int idx = blockIdx.x * 256 + threadIdx.x;    // < 64*2048*32
  int d  = idx & 31;
  int s  = (idx >> 5) & (S_LEN - 1);
  int bh = idx >> 16;
  long base = ((long)bh * S_LEN + s) * 64 + d;
  // inv_freq = 10000^(-d/32) = exp2(-d * log2(10000)/32)
  float inv = exp2f((float)d * -0.41524101186092026f);
  float ang = (float)s * inv;
  float sn, cs;
  __sincosf(ang, &sn, &cs);
  float x1 = (float)q[base], x2 = (float)q[base + 32];
  q[base]      = (bf16)(x1 * cs - x2 * sn);
  q[base + 32] = (bf16)(x2 * cs + x1 * sn);
  float y1 = (float)k[base], y2 = (float)k[base + 32];
  k[base]      = (bf16)(y1 * cs - y2 * sn);
  k[base + 32] = (bf16)(y2 * cs + y1 * sn);
}

// ---------------- GEMM: C = A @ W^T (+bias), both operands K-major ----------------
// MODE 0: A = x_bf (8192x1024), W = {Wq,Wk,Wv} by blockIdx.z; out -> per-head q/k (BH,S,64), v transposed (BH,64,S), bf16
// MODE 1: A = o_ws (8192x1024) bf16, W = Wo; out -> d_out f32 + bias
template<int MODE>
__global__ __launch_bounds__(256) void gemm_bt_kernel(
    const bf16* __restrict__ A, const bf16* __restrict__ Wb,
    const float* __restrict__ bias0, const float* __restrict__ bias1, const float* __restrict__ bias2,
    bf16* __restrict__ q_ws, bf16* __restrict__ k_ws, bf16* __restrict__ v_t,
    float* __restrict__ dout)
{
  __shared__ __align__(16) bf16 As[128 * 32];
  __shared__ __align__(16) bf16 Bs[128 * 32];
  const int tid  = threadIdx.x;
  const int lane = tid & 63, wid = tid >> 6;
  const int ql = lane & 15, lg = lane >> 4;
  const int wm = wid >> 1, wn = wid & 1;
  const int bm = blockIdx.x, bn = blockIdx.y;
  const int z  = (MODE == 0) ? blockIdx.z : 0;

  const bf16* Ag = A  + (long)bm * 128 * 1024;
  const bf16* Bg = Wb + (long)z * 1024 * 1024 + (long)bn * 128 * 1024;

  f32x4_t acc[4][4];
  const f32x4_t zero4 = { 0.f, 0.f, 0.f, 0.f };
  #pragma unroll
  for (int i = 0; i < 4; i++)
    #pragma unroll
    for (int j = 0; j < 4; j++) acc[i][j] = zero4;

  for (int k0 = 0; k0 < 1024; k0 += 32) {
    __syncthreads();                       // previous tile's ds_reads done
    #pragma unroll
    for (int r = 0; r < 2; r++) {
      int tt = tid + r * 256;
      int row = tt >> 2, kc = (tt & 3) * 8;
      glds16(Ag + (long)row * 1024 + k0 + kc, (void*)&As[tt * 8]);
    }
    #pragma unroll
    for (int r = 0; r < 2; r++) {
      int tt = tid + r * 256;
      int row = tt >> 2, kc = (tt & 3) * 8;
      glds16(Bg + (long)row * 1024 + k0 + kc, (void*)&Bs[tt * 8]);
    }
    __syncthreads();                       // compiler drains vmcnt before barrier

    bf16x8_t af[4], bf_[4];
    #pragma unroll
    for (int m = 0; m < 4; m++) af[m]  = *(const bf16x8_t*)&As[(wm * 64 + m * 16 + ql) * 32 + lg * 8];
    #pragma unroll
    for (int n = 0; n < 4; n++) bf_[n] = *(const bf16x8_t*)&Bs[(wn * 64 + n * 16 + ql) * 32 + lg * 8];
    #pragma unroll
    for (int m = 0; m < 4; m++)
      #pragma unroll
      for (int n = 0; n < 4; n++)
        acc[m][n] = __builtin_amdgcn_mfma_f32_16x16x32_bf16(af[m], bf_[n], acc[m][n], 0, 0, 0);
  }

  // epilogue: C/D layout col=lane&15, row=(lane>>4)*4+reg  [m89/m91]
  if (MODE == 1) {
    #pragma unroll
    for (int m = 0; m < 4; m++) {
      int rb = bm * 128 + wm * 64 + m * 16 + lg * 4;
      #pragma unroll
      for (int n = 0; n < 4; n++) {
        int colg = bn * 128 + wn * 64 + n * 16 + ql;
        float bb = bias0[colg];
        #pragma unroll
        for (int r = 0; r < 4; r++)
          dout[(long)(rb + r) * 1024 + colg] = acc[m][n][r] + bb;
      }
    }
  } else {
    const float* bias = (z == 0) ? bias0 : (z == 1) ? bias1 : bias2;
    #pragma unroll
    for (int m = 0; m < 4; m++) {
      int rb = bm * 128 + wm * 64 + m * 16 + lg * 4;     // global token row (mult of 4)
      int bb_ = rb >> 11;                                 // batch
      int s0  = rb & 2047;                                // seq pos of reg 0
      #pragma unroll
      for (int n = 0; n < 4; n++) {
        int colg = bn * 128 + wn * 64 + n * 16 + ql;
        int h = colg >> 6, d = colg & 63;
        float bb = bias[colg];
        if (z == 2) {
          // v transposed: v_t[(bh*64 + d)*2048 + s]; regs = 4 consecutive s -> 8B store
          ushort4 pkt;
          pkt.x = __builtin_bit_cast(unsigned short, (bf16)(acc[m][n][0] + bb));
          pkt.y = __builtin_bit_cast(unsigned short, (bf16)(acc[m][n][1] + bb));
          pkt.z = __builtin_bit_cast(unsigned short, (bf16)(acc[m][n][2] + bb));
          pkt.w = __builtin_bit_cast(unsigned short, (bf16)(acc[m][n][3] + bb));
          *(ushort4*)&v_t[((long)(bb_ * NHEAD + h) * 64 + d) * S_LEN + s0] = pkt;
        } else {
          bf16* dst = z ? k_ws : q_ws;
          long base = ((long)(bb_ * NHEAD + h) * S_LEN + s0) * 64 + d;
          #pragma unroll
          for (int r = 0; r < 4; r++)
            dst[base + (long)r * 64] = (bf16)(acc[m][n][r] + bb);
        }
      }
    }
  }
}

// ---------------- flash attention: 1 wave = 16 q rows, KVBLK = 32 ----------------
// Swapped QK^T: S^T = K_tile(16k x 64d) . Q^T(64d x 16q) -> lane col=q, rows=k.
__global__ __launch_bounds__(256) void attn_kernel(const bf16* __restrict__ qw, const bf16* __restrict__ kw,
                                                   const bf16* __restrict__ vt, bf16* __restrict__ ow,
                                                   const int* __restrict__ lens)
{
  const int tid = threadIdx.x, lane = tid & 63, wid = tid >> 6;
  const int ql = lane & 15, lg = lane >> 4;
  const int bh = blockIdx.y, b = bh >> 4, h = bh & 15;
  const int len = lens[b];
  const int q0 = blockIdx.x * 64 + wid * 16;
  const int qg = q0 + ql;

  const bf16* qh = qw + (long)bh * S_LEN * 64;
  const bf16* kh = kw + (long)bh * S_LEN * 64;
  const bf16* vh = vt + (long)bh * 64 * S_LEN;
  bf16* orow = ow + ((long)b * S_LEN + qg) * 1024 + h * 64;

  if (q0 >= len) {  // whole wave masked out -> zero rows (proj then yields bo)
    ushort4 zz; zz.x = zz.y = zz.z = zz.w = 0;
    #pragma unroll
    for (int n = 0; n < 4; n++) *(ushort4*)&orow[n * 16 + lg * 4] = zz;
    return;
  }

  // Q^T B-operand frags: lane reads Q[q=ql][d = dc*32 + lg*8 .. +7]
  bf16x8_t qb[2];
  #pragma unroll
  for (int dc = 0; dc < 2; dc++)
    qb[dc] = *(const bf16x8_t*)&qh[(long)qg * 64 + dc * 32 + lg * 8];

  const f32x4_t zero4 = { 0.f, 0.f, 0.f, 0.f };
  f32x4_t oacc[4];  // O^T accum: frag n -> dv in [n*16, n*16+16)
  #pragma unroll
  for (int n = 0; n < 4; n++) oacc[n] = zero4;

  float m_run = -1e30f, l_run = 0.f;
  const int kend = min(q0 + 15, len - 1);

  for (int k0 = 0; k0 <= kend; k0 += 32) {
    f32x4_t st0 = zero4, st1 = zero4;      // S^T slices: k in [k0,k0+16) and [k0+16,k0+32)
    #pragma unroll
    for (int dc = 0; dc < 2; dc++) {
      bf16x8_t a0 = *(const bf16x8_t*)&kh[(long)(k0 + ql) * 64 + dc * 32 + lg * 8];
      bf16x8_t a1 = *(const bf16x8_t*)&kh[(long)(k0 + 16 + ql) * 64 + dc * 32 + lg * 8];
      st0 = __builtin_amdgcn_mfma_f32_16x16x32_bf16(a0, qb[dc], st0, 0, 0, 0);
      st1 = __builtin_amdgcn_mfma_f32_16x16x32_bf16(a1, qb[dc], st1, 0, 0, 0);
    }
    // mask + scale; lane holds k = k0 + lg*4 + r (st0) and +16 (st1) for its q column
    float pv[8];
    float mloc = -1e30f;
    #pragma unroll
    for (int r = 0; r < 4; r++) {
      int kg0 = k0 + lg * 4 + r;
      int kg1 = kg0 + 16;
      float s0v = (kg0 <= qg && kg0 < len) ? st0[r] * 0.125f : -1e30f;
      float s1v = (kg1 <= qg && kg1 < len) ? st1[r] * 0.125f : -1e30f;
      pv[r] = s0v; pv[4 + r] = s1v;
      mloc = fmaxf(mloc, fmaxf(s0v, s1v));
    }
    mloc = fmaxf(mloc, __shfl_xor(mloc, 16));
    mloc = fmaxf(mloc, __shfl_xor(mloc, 32));
    float m_new = fmaxf(m_run, mloc);
    float sc = __expf(m_run - m_new);
    float ps = 0.f;
    #pragma unroll
    for (int i = 0; i < 8; i++) { pv[i] = __expf(pv[i] - m_new); ps += pv[i]; }
    ps += __shfl_xor(ps, 16);
    ps += __shfl_xor(ps, 32);
    l_run = l_run * sc + ps;
    m_run = m_new;
    #pragma unroll
    for (int n = 0; n < 4; n++) oacc[n] = oacc[n] * sc;

    // Build P^T B-operand frag (32k x 16q). Lane l=q+16g needs k=8g..8g+7.
    // Packed source words: lane q+16*gs holds (stA) k=4gs..4gs+3 -> pa0=(k4gs,k4gs+1), pa1=(+2,+3);
    // (stB) k=16+4gs.. -> pb0/pb1. Mapping: g=0: stA lanes q,q+16; g=1: stA q+32,q+48;
    // g=2: stB lanes q,q+16; g=3: stB q+32,q+48.
    unsigned pa0 = pk2(pv[0], pv[1]), pa1 = pk2(pv[2], pv[3]);
    unsigned pb0 = pk2(pv[4], pv[5]), pb1 = pk2(pv[6], pv[7]);
    const int srcA = ql + 32 * (lg & 1);
    const int srcB = srcA + 16;
    unsigned t0 = (unsigned)__shfl((int)pa0, srcA), t1 = (unsigned)__shfl((int)pa1, srcA);
    unsigned t2 = (unsigned)__shfl((int)pa0, srcB), t3 = (unsigned)__shfl((int)pa1, srcB);
    unsigned u0 = (unsigned)__shfl((int)pb0, srcA), u1 = (unsigned)__shfl((int)pb1, srcA);
    unsigned u2 = (unsigned)__shfl((int)pb0, srcB), u3 = (unsigned)__shfl((int)pb1, srcB);
    bool hi = (lg >= 2);
    u32x4_t wv;
    wv.x = hi ? u0 : t0;
    wv.y = hi ? u1 : t1;
    wv.z = hi ? u2 : t2;
    wv.w = hi ? u3 : t3;
    bf16x8_t pfrag = __builtin_bit_cast(bf16x8_t, wv);

    // O^T += V^T_slice(16dv x 32k) . P^T(32k x 16q); V^T rows contiguous (v stored transposed)
    #pragma unroll
    for (int n = 0; n < 4; n++) {
      bf16x8_t av = *(const bf16x8_t*)&vh[(long)(n * 16 + ql) * S_LEN + k0 + lg * 8];
      oacc[n] = __builtin_amdgcn_mfma_f32_16x16x32_bf16(av, pfrag, oacc[n], 0, 0, 0);
    }
  }

  float rinv = (qg < len) ? (1.0f / l_run) : 0.f;  // masked rows -> exact 0
  #pragma unroll
  for (int n = 0; n < 4; n++) {
    ushort4 pkt;
    pkt.x = __builtin_bit_cast(unsigned short, (bf16)(oacc[n][0] * rinv));
    pkt.y = __builtin_bit_cast(unsigned short, (bf16)(oacc[n][1] * rinv));
    pkt.z = __builtin_bit_cast(unsigned short, (bf16)(oacc[n][2] * rinv));
    pkt.w = __builtin_bit_cast(unsigned short, (bf16)(oacc[n][3] * rinv));
    *(ushort4*)&orow[n * 16 + lg * 4] = pkt;
  }
}

// ---------------- launch ----------------
extern "C" void kernel_launch(void* const* d_in, const int* in_sizes, int n_in,
                              void* d_out, int out_size, void* d_ws, size_t ws_size,
                              hipStream_t stream)
{
  const float* X  = (const float*)d_in[0];
  const float* Wq = (const float*)d_in[1];
  const float* bq = (const float*)d_in[2];
  const float* Wk = (const float*)d_in[3];
  const float* bk = (const float*)d_in[4];
  const float* Wv = (const float*)d_in[5];
  const float* bv = (const float*)d_in[6];
  const float* Wo = (const float*)d_in[7];
  const float* bo = (const float*)d_in[8];
  const int* lens = (const int*)d_in[9];
  float* out = (float*)d_out;

  char* ws = (char*)d_ws;
  bf16* x_bf = (bf16*)(ws);                         // 16 MiB: X as bf16 (8192 x 1024)
  bf16* w_bf = (bf16*)(ws + (16u << 20));           //  8 MiB: Wq,Wk,Wv,Wo bf16
  bf16* q_ws = (bf16*)(ws + (24u << 20));           // 16 MiB: (BH,S,64)
  bf16* k_ws = (bf16*)(ws + (40u << 20));           // 16 MiB: (BH,S,64)
  bf16* v_t  = (bf16*)(ws + (56u << 20));           // 16 MiB: (BH,64,S)
  bf16* o_ws = (bf16*)(ws + (72u << 20));           // 16 MiB: (B*S, 1024)

  cvt_x_kernel<<<8192, 256, 0, stream>>>((const float4*)X, (bf16x4_t*)x_bf);
  cvt_w_kernel<<<4096, 256, 0, stream>>>(Wq, Wk, Wv, Wo, (bf16x4_t*)w_bf);
  gemm_bt_kernel<0><<<dim3(64, 8, 3), 256, 0, stream>>>(x_bf, w_bf, bq, bk, bv,
                                                        q_ws, k_ws, v_t, nullptr);
  rope_kernel<<<16384, 256, 0, stream>>>(q_ws, k_ws);
  attn_kernel<<<dim3(32, 64), 256, 0, stream>>>(q_ws, k_ws, v_t, o_ws, lens);
  gemm_bt_kernel<1><<<dim3(64, 8, 1), 256, 0, stream>>>(o_ws, w_bf + 3u * 1048576u, bo, bo, bo,
                                                        q_ws, k_ws, v_t, out);
}

// Round 3
// 370.124 us; speedup vs baseline: 1.2703x; 1.2703x over previous
//
#include <hip/hip_runtime.h>

typedef __bf16 bf16;
typedef __bf16 bf16x4_t __attribute__((ext_vector_type(4)));
typedef __bf16 bf16x8_t __attribute__((ext_vector_type(8)));
typedef float  f32x4_t  __attribute__((ext_vector_type(4)));
typedef unsigned int u32x4_t __attribute__((ext_vector_type(4)));

#define S_LEN 2048
#define NHEAD 16
#define NBH   64   // B*H

// async global->LDS, 16B per lane, linear dest (wave-uniform base + lane*16)
static __device__ __forceinline__ void glds16(const void* g, void* l) {
  __builtin_amdgcn_global_load_lds(
      (const __attribute__((address_space(1))) unsigned int*)g,
      (__attribute__((address_space(3))) unsigned int*)l, 16, 0, 0);
}

static __device__ __forceinline__ unsigned pk2(float lo, float hi) {
  unsigned short a = __builtin_bit_cast(unsigned short, (bf16)lo);
  unsigned short b = __builtin_bit_cast(unsigned short, (bf16)hi);
  return (unsigned)a | ((unsigned)b << 16);
}

// ---------------- f32 -> bf16 converts ----------------
__global__ __launch_bounds__(256) void cvt_x_kernel(const float4* __restrict__ in,
                                                    bf16x4_t* __restrict__ out) {
  int i = blockIdx.x * 256 + threadIdx.x;   // exactly 2097152 threads
  float4 v = in[i];
  bf16x4_t o = { (bf16)v.x, (bf16)v.y, (bf16)v.z, (bf16)v.w };
  out[i] = o;
}

__global__ __launch_bounds__(256) void cvt_w_kernel(const float* __restrict__ w0, const float* __restrict__ w1,
                                                    const float* __restrict__ w2, const float* __restrict__ w3,
                                                    bf16x4_t* __restrict__ out) {
  int i = blockIdx.x * 256 + threadIdx.x;   // exactly 1048576 threads (4 x 262144 float4)
  int sel = i >> 18;
  int j = i & 262143;
  const float4* src = (const float4*)(sel == 0 ? w0 : sel == 1 ? w1 : sel == 2 ? w2 : w3);
  float4 v = src[j];
  bf16x4_t o = { (bf16)v.x, (bf16)v.y, (bf16)v.z, (bf16)v.w };
  out[i] = o;
}

// ---------------- GEMM: C = A @ W^T (+bias), both operands K-major ----------------
// MODE 0: A = x_bf; W = {Wq,Wk,Wv} by blockIdx.z. z<2 -> fused RoPE, out per-head q/k (BH,S,64);
//         z==2 -> v transposed (BH,64,S), bf16
// MODE 1: A = o_ws bf16, W = Wo; out -> d_out f32 + bias
template<int MODE>
__global__ __launch_bounds__(256) void gemm_bt_kernel(
    const bf16* __restrict__ A, const bf16* __restrict__ Wb,
    const float* __restrict__ bias0, const float* __restrict__ bias1, const float* __restrict__ bias2,
    bf16* __restrict__ q_ws, bf16* __restrict__ k_ws, bf16* __restrict__ v_t,
    float* __restrict__ dout)
{
  __shared__ __align__(16) bf16 As[128 * 32];
  __shared__ __align__(16) bf16 Bs[128 * 32];
  const int tid  = threadIdx.x;
  const int lane = tid & 63, wid = tid >> 6;
  const int ql = lane & 15, lg = lane >> 4;
  const int wm = wid >> 1, wn = wid & 1;
  const int bm = blockIdx.x, bn = blockIdx.y;
  const int z  = (MODE == 0) ? blockIdx.z : 0;

  const bf16* Ag = A  + (long)bm * 128 * 1024;
  const bf16* Bg = Wb + (long)z * 1024 * 1024 + (long)bn * 128 * 1024;

  f32x4_t acc[4][4];
  const f32x4_t zero4 = { 0.f, 0.f, 0.f, 0.f };
  #pragma unroll
  for (int i = 0; i < 4; i++)
    #pragma unroll
    for (int j = 0; j < 4; j++) acc[i][j] = zero4;

  for (int k0 = 0; k0 < 1024; k0 += 32) {
    __syncthreads();                       // previous tile's ds_reads done
    #pragma unroll
    for (int r = 0; r < 2; r++) {
      int tt = tid + r * 256;
      int row = tt >> 2, kc = (tt & 3) * 8;
      glds16(Ag + (long)row * 1024 + k0 + kc, (void*)&As[tt * 8]);
    }
    #pragma unroll
    for (int r = 0; r < 2; r++) {
      int tt = tid + r * 256;
      int row = tt >> 2, kc = (tt & 3) * 8;
      glds16(Bg + (long)row * 1024 + k0 + kc, (void*)&Bs[tt * 8]);
    }
    __syncthreads();                       // compiler drains vmcnt before barrier

    bf16x8_t af[4], bf_[4];
    #pragma unroll
    for (int m = 0; m < 4; m++) af[m]  = *(const bf16x8_t*)&As[(wm * 64 + m * 16 + ql) * 32 + lg * 8];
    #pragma unroll
    for (int n = 0; n < 4; n++) bf_[n] = *(const bf16x8_t*)&Bs[(wn * 64 + n * 16 + ql) * 32 + lg * 8];
    #pragma unroll
    for (int m = 0; m < 4; m++)
      #pragma unroll
      for (int n = 0; n < 4; n++)
        acc[m][n] = __builtin_amdgcn_mfma_f32_16x16x32_bf16(af[m], bf_[n], acc[m][n], 0, 0, 0);
  }

  // epilogue: C/D layout col=lane&15, row=(lane>>4)*4+reg  [m89/m91]
  if (MODE == 1) {
    #pragma unroll
    for (int m = 0; m < 4; m++) {
      int rb = bm * 128 + wm * 64 + m * 16 + lg * 4;
      #pragma unroll
      for (int n = 0; n < 4; n++) {
        int colg = bn * 128 + wn * 64 + n * 16 + ql;
        float bb = bias0[colg];
        #pragma unroll
        for (int r = 0; r < 4; r++)
          dout[(long)(rb + r) * 1024 + colg] = acc[m][n][r] + bb;
      }
    }
  } else if (z == 2) {
    #pragma unroll
    for (int m = 0; m < 4; m++) {
      int rb = bm * 128 + wm * 64 + m * 16 + lg * 4;     // global token row (mult of 4)
      int bb_ = rb >> 11;                                 // batch
      int s0  = rb & 2047;                                // seq pos of reg 0
      #pragma unroll
      for (int n = 0; n < 4; n++) {
        int colg = bn * 128 + wn * 64 + n * 16 + ql;
        int h = colg >> 6, d = colg & 63;
        float bb = bias2[colg];
        // v transposed: v_t[(bh*64 + d)*2048 + s]; regs = 4 consecutive s -> 8B store
        ushort4 pkt;
        pkt.x = __builtin_bit_cast(unsigned short, (bf16)(acc[m][n][0] + bb));
        pkt.y = __builtin_bit_cast(unsigned short, (bf16)(acc[m][n][1] + bb));
        pkt.z = __builtin_bit_cast(unsigned short, (bf16)(acc[m][n][2] + bb));
        pkt.w = __builtin_bit_cast(unsigned short, (bf16)(acc[m][n][3] + bb));
        *(ushort4*)&v_t[((long)(bb_ * NHEAD + h) * 64 + d) * S_LEN + s0] = pkt;
      }
    }
  } else {
    // q or k with FUSED RoPE. For fixed (m,r) this thread holds cols d=n*16+ql (n=0..3)
    // of ONE head => pairs (n, n+2) are exactly (d, d+32) — rotate in-register.
    const float* bias = z ? bias1 : bias0;
    bf16* dst = z ? k_ws : q_ws;
    #pragma unroll
    for (int m = 0; m < 4; m++) {
      int rb = bm * 128 + wm * 64 + m * 16 + lg * 4;
      int bb_ = rb >> 11;
      int s0  = rb & 2047;
      #pragma unroll
      for (int n = 0; n < 2; n++) {
        int colg = bn * 128 + wn * 64 + n * 16 + ql;
        int h = colg >> 6, d = colg & 63;                 // d in [0,32)
        float b1 = bias[colg], b2 = bias[colg + 32];
        // inv_freq = 10000^(-d/32) = exp2(-d * log2(10000)/32)
        float inv = exp2f((float)d * -0.41524101186092026f);
        #pragma unroll
        for (int r = 0; r < 4; r++) {
          int s = s0 + r;
          float ang = (float)s * inv;
          float sn, cs;
          __sincosf(ang, &sn, &cs);
          float x1 = acc[m][n][r] + b1;
          float x2 = acc[m][n + 2][r] + b2;
          long base = ((long)(bb_ * NHEAD + h) * S_LEN + s) * 64;
          dst[base + d]      = (bf16)(x1 * cs - x2 * sn);
          dst[base + d + 32] = (bf16)(x2 * cs + x1 * sn);
        }
      }
    }
  }
}

// ---------------- flash attention: 1 wave = 32 q rows (2 x 16q groups), KVBLK = 32 ----------------
// Swapped QK^T: S^T = K_tile(16k x 64d) . Q^T(64d x 16q) -> lane col=q, rows=k.
// K and V fragment loads are shared between the two q-groups (2x arithmetic intensity + ILP).
__global__ __launch_bounds__(256) void attn_kernel(const bf16* __restrict__ qw, const bf16* __restrict__ kw,
                                                   const bf16* __restrict__ vt, bf16* __restrict__ ow,
                                                   const int* __restrict__ lens)
{
  const int tid = threadIdx.x, lane = tid & 63, wid = tid >> 6;
  const int ql = lane & 15, lg = lane >> 4;
  const int bh = blockIdx.y, b = bh >> 4, h = bh & 15;
  const int len = lens[b];
  // reversed q order: longest causal tiles dispatch first (tail-first scheduling)
  const int q0 = (15 - (int)blockIdx.x) * 128 + wid * 32;   // wave owns q0..q0+31
  const int qgA = q0 + ql, qgB = qgA + 16;

  const bf16* qh = qw + (long)bh * S_LEN * 64;
  const bf16* kh = kw + (long)bh * S_LEN * 64;
  const bf16* vh = vt + (long)bh * 64 * S_LEN;
  bf16* orowA = ow + ((long)b * S_LEN + qgA) * 1024 + h * 64;
  bf16* orowB = orowA + 16l * 1024;

  if (q0 >= len) {  // whole wave masked out -> zero rows (proj then yields bo)
    ushort4 zz; zz.x = zz.y = zz.z = zz.w = 0;
    #pragma unroll
    for (int n = 0; n < 4; n++) {
      *(ushort4*)&orowA[n * 16 + lg * 4] = zz;
      *(ushort4*)&orowB[n * 16 + lg * 4] = zz;
    }
    return;
  }

  // Q^T B-operand frags: lane reads Q[q][d = dc*32 + lg*8 .. +7]
  bf16x8_t qbA[2], qbB[2];
  #pragma unroll
  for (int dc = 0; dc < 2; dc++) {
    qbA[dc] = *(const bf16x8_t*)&qh[(long)qgA * 64 + dc * 32 + lg * 8];
    qbB[dc] = *(const bf16x8_t*)&qh[(long)qgB * 64 + dc * 32 + lg * 8];
  }

  const f32x4_t zero4 = { 0.f, 0.f, 0.f, 0.f };
  f32x4_t oaccA[4], oaccB[4];  // O^T accum: frag n -> dv in [n*16, n*16+16)
  #pragma unroll
  for (int n = 0; n < 4; n++) { oaccA[n] = zero4; oaccB[n] = zero4; }

  float mA = -1e30f, lA = 0.f, mB = -1e30f, lB = 0.f;
  const int kend = min(q0 + 31, len - 1);

  // masked-softmax + P^T-fragment rebuild for one 16-q group
  auto sm_group = [&](const f32x4_t& st0, const f32x4_t& st1, int qg, int k0,
                      float& m_run, float& l_run, f32x4_t* oacc) -> bf16x8_t {
    float pv[8];
    float mloc = -1e30f;
    #pragma unroll
    for (int r = 0; r < 4; r++) {
      int kg0 = k0 + lg * 4 + r;
      int kg1 = kg0 + 16;
      float s0v = (kg0 <= qg && kg0 < len) ? st0[r] * 0.125f : -1e30f;
      float s1v = (kg1 <= qg && kg1 < len) ? st1[r] * 0.125f : -1e30f;
      pv[r] = s0v; pv[4 + r] = s1v;
      mloc = fmaxf(mloc, fmaxf(s0v, s1v));
    }
    mloc = fmaxf(mloc, __shfl_xor(mloc, 16));
    mloc = fmaxf(mloc, __shfl_xor(mloc, 32));
    float m_new = fmaxf(m_run, mloc);
    float sc = __expf(m_run - m_new);
    float ps = 0.f;
    #pragma unroll
    for (int i = 0; i < 8; i++) { pv[i] = __expf(pv[i] - m_new); ps += pv[i]; }
    ps += __shfl_xor(ps, 16);
    ps += __shfl_xor(ps, 32);
    l_run = l_run * sc + ps;
    m_run = m_new;
    #pragma unroll
    for (int n = 0; n < 4; n++) oacc[n] = oacc[n] * sc;

    // Build P^T B-operand frag (32k x 16q). Lane l=q+16g needs k=8g..8g+7.
    unsigned pa0 = pk2(pv[0], pv[1]), pa1 = pk2(pv[2], pv[3]);
    unsigned pb0 = pk2(pv[4], pv[5]), pb1 = pk2(pv[6], pv[7]);
    const int srcA = ql + 32 * (lg & 1);
    const int srcB = srcA + 16;
    unsigned t0 = (unsigned)__shfl((int)pa0, srcA), t1 = (unsigned)__shfl((int)pa1, srcA);
    unsigned t2 = (unsigned)__shfl((int)pa0, srcB), t3 = (unsigned)__shfl((int)pa1, srcB);
    unsigned u0 = (unsigned)__shfl((int)pb0, srcA), u1 = (unsigned)__shfl((int)pb1, srcA);
    unsigned u2 = (unsigned)__shfl((int)pb0, srcB), u3 = (unsigned)__shfl((int)pb1, srcB);
    bool hi = (lg >= 2);
    u32x4_t wv;
    wv.x = hi ? u0 : t0;
    wv.y = hi ? u1 : t1;
    wv.z = hi ? u2 : t2;
    wv.w = hi ? u3 : t3;
    return __builtin_bit_cast(bf16x8_t, wv);
  };

  for (int k0 = 0; k0 <= kend; k0 += 32) {
    // shared K fragments: rows k0+ql and k0+16+ql
    bf16x8_t kf0[2], kf1[2];
    #pragma unroll
    for (int dc = 0; dc < 2; dc++) {
      kf0[dc] = *(const bf16x8_t*)&kh[(long)(k0 + ql) * 64 + dc * 32 + lg * 8];
      kf1[dc] = *(const bf16x8_t*)&kh[(long)(k0 + 16 + ql) * 64 + dc * 32 + lg * 8];
    }
    f32x4_t sA0 = zero4, sA1 = zero4, sB0 = zero4, sB1 = zero4;
    #pragma unroll
    for (int dc = 0; dc < 2; dc++) {
      sA0 = __builtin_amdgcn_mfma_f32_16x16x32_bf16(kf0[dc], qbA[dc], sA0, 0, 0, 0);
      sA1 = __builtin_amdgcn_mfma_f32_16x16x32_bf16(kf1[dc], qbA[dc], sA1, 0, 0, 0);
      sB0 = __builtin_amdgcn_mfma_f32_16x16x32_bf16(kf0[dc], qbB[dc], sB0, 0, 0, 0);
      sB1 = __builtin_amdgcn_mfma_f32_16x16x32_bf16(kf1[dc], qbB[dc], sB1, 0, 0, 0);
    }

    bf16x8_t pfA = sm_group(sA0, sA1, qgA, k0, mA, lA, oaccA);
    bf16x8_t pfB = sm_group(sB0, sB1, qgB, k0, mB, lB, oaccB);

    // O^T += V^T_slice(16dv x 32k) . P^T ; V fragments shared between groups
    #pragma unroll
    for (int n = 0; n < 4; n++) {
      bf16x8_t av = *(const bf16x8_t*)&vh[(long)(n * 16 + ql) * S_LEN + k0 + lg * 8];
      oaccA[n] = __builtin_amdgcn_mfma_f32_16x16x32_bf16(av, pfA, oaccA[n], 0, 0, 0);
      oaccB[n] = __builtin_amdgcn_mfma_f32_16x16x32_bf16(av, pfB, oaccB[n], 0, 0, 0);
    }
  }

  float rinvA = (qgA < len) ? (1.0f / lA) : 0.f;  // masked rows -> exact 0
  float rinvB = (qgB < len) ? (1.0f / lB) : 0.f;
  #pragma unroll
  for (int n = 0; n < 4; n++) {
    ushort4 pA, pB;
    pA.x = __builtin_bit_cast(unsigned short, (bf16)(oaccA[n][0] * rinvA));
    pA.y = __builtin_bit_cast(unsigned short, (bf16)(oaccA[n][1] * rinvA));
    pA.z = __builtin_bit_cast(unsigned short, (bf16)(oaccA[n][2] * rinvA));
    pA.w = __builtin_bit_cast(unsigned short, (bf16)(oaccA[n][3] * rinvA));
    pB.x = __builtin_bit_cast(unsigned short, (bf16)(oaccB[n][0] * rinvB));
    pB.y = __builtin_bit_cast(unsigned short, (bf16)(oaccB[n][1] * rinvB));
    pB.z = __builtin_bit_cast(unsigned short, (bf16)(oaccB[n][2] * rinvB));
    pB.w = __builtin_bit_cast(unsigned short, (bf16)(oaccB[n][3] * rinvB));
    *(ushort4*)&orowA[n * 16 + lg * 4] = pA;
    *(ushort4*)&orowB[n * 16 + lg * 4] = pB;
  }
}

// ---------------- launch ----------------
extern "C" void kernel_launch(void* const* d_in, const int* in_sizes, int n_in,
                              void* d_out, int out_size, void* d_ws, size_t ws_size,
                              hipStream_t stream)
{
  const float* X  = (const float*)d_in[0];
  const float* Wq = (const float*)d_in[1];
  const float* bq = (const float*)d_in[2];
  const float* Wk = (const float*)d_in[3];
  const float* bk = (const float*)d_in[4];
  const float* Wv = (const float*)d_in[5];
  const float* bv = (const float*)d_in[6];
  const float* Wo = (const float*)d_in[7];
  const float* bo = (const float*)d_in[8];
  const int* lens = (const int*)d_in[9];
  float* out = (float*)d_out;

  char* ws = (char*)d_ws;
  bf16* x_bf = (bf16*)(ws);                         // 16 MiB: X as bf16 (8192 x 1024)
  bf16* w_bf = (bf16*)(ws + (16u << 20));           //  8 MiB: Wq,Wk,Wv,Wo bf16
  bf16* q_ws = (bf16*)(ws + (24u << 20));           // 16 MiB: (BH,S,64)
  bf16* k_ws = (bf16*)(ws + (40u << 20));           // 16 MiB: (BH,S,64)
  bf16* v_t  = (bf16*)(ws + (56u << 20));           // 16 MiB: (BH,64,S)
  bf16* o_ws = (bf16*)(ws + (72u << 20));           // 16 MiB: (B*S, 1024)

  cvt_x_kernel<<<8192, 256, 0, stream>>>((const float4*)X, (bf16x4_t*)x_bf);
  cvt_w_kernel<<<4096, 256, 0, stream>>>(Wq, Wk, Wv, Wo, (bf16x4_t*)w_bf);
  gemm_bt_kernel<0><<<dim3(64, 8, 3), 256, 0, stream>>>(x_bf, w_bf, bq, bk, bv,
                                                        q_ws, k_ws, v_t, nullptr);
  attn_kernel<<<dim3(16, 64), 256, 0, stream>>>(q_ws, k_ws, v_t, o_ws, lens);
  gemm_bt_kernel<1><<<dim3(64, 8, 1), 256, 0, stream>>>(o_ws, w_bf + 3u * 1048576u, bo, bo, bo,
                                                        q_ws, k_ws, v_t, out);
}

// Round 5
// 321.715 us; speedup vs baseline: 1.4615x; 1.1505x over previous
//
#include <hip/hip_runtime.h>

typedef __bf16 bf16;
typedef __bf16 bf16x4_t __attribute__((ext_vector_type(4)));
typedef __bf16 bf16x8_t __attribute__((ext_vector_type(8)));
typedef float  f32x4_t  __attribute__((ext_vector_type(4)));
typedef float  f32x16_t __attribute__((ext_vector_type(16)));
typedef unsigned int u32x4_t __attribute__((ext_vector_type(4)));

#define S_LEN 2048
#define NHEAD 16
#define NBH   64   // B*H

// async global->LDS, 16B per lane, linear dest (wave-uniform base + lane*16)
static __device__ __forceinline__ void glds16(const void* g, void* l) {
  __builtin_amdgcn_global_load_lds(
      (const __attribute__((address_space(1))) unsigned int*)g,
      (__attribute__((address_space(3))) unsigned int*)l, 16, 0, 0);
}

static __device__ __forceinline__ unsigned pk2(float lo, float hi) {
  unsigned short a = __builtin_bit_cast(unsigned short, (bf16)lo);
  unsigned short b = __builtin_bit_cast(unsigned short, (bf16)hi);
  return (unsigned)a | ((unsigned)b << 16);
}

// ---------------- f32 -> bf16 converts ----------------
__global__ __launch_bounds__(256) void cvt_x_kernel(const float4* __restrict__ in,
                                                    bf16x4_t* __restrict__ out) {
  int i = blockIdx.x * 256 + threadIdx.x;   // exactly 2097152 threads
  float4 v = in[i];
  bf16x4_t o = { (bf16)v.x, (bf16)v.y, (bf16)v.z, (bf16)v.w };
  out[i] = o;
}

__global__ __launch_bounds__(256) void cvt_w_kernel(const float* __restrict__ w0, const float* __restrict__ w1,
                                                    const float* __restrict__ w2, const float* __restrict__ w3,
                                                    bf16x4_t* __restrict__ out) {
  int i = blockIdx.x * 256 + threadIdx.x;   // exactly 1048576 threads (4 x 262144 float4)
  int sel = i >> 18;
  int j = i & 262143;
  const float4* src = (const float4*)(sel == 0 ? w0 : sel == 1 ? w1 : sel == 2 ? w2 : w3);
  float4 v = src[j];
  bf16x4_t o = { (bf16)v.x, (bf16)v.y, (bf16)v.z, (bf16)v.w };
  out[i] = o;
}

// ---------------- GEMM: C = A @ W^T (+bias), both operands K-major ----------------
// MODE 0: A = x_bf; W = {Wq,Wk,Wv} by blockIdx.z. z<2 -> fused RoPE, out per-head q/k (BH,S,64);
//         z==2 -> v transposed (BH,64,S), bf16
// MODE 1: A = o_ws bf16, W = Wo; out -> d_out f32 + bias
template<int MODE>
__global__ __launch_bounds__(256) void gemm_bt_kernel(
    const bf16* __restrict__ A, const bf16* __restrict__ Wb,
    const float* __restrict__ bias0, const float* __restrict__ bias1, const float* __restrict__ bias2,
    bf16* __restrict__ q_ws, bf16* __restrict__ k_ws, bf16* __restrict__ v_t,
    float* __restrict__ dout)
{
  __shared__ __align__(16) bf16 As[128 * 32];
  __shared__ __align__(16) bf16 Bs[128 * 32];
  const int tid  = threadIdx.x;
  const int lane = tid & 63, wid = tid >> 6;
  const int ql = lane & 15, lg = lane >> 4;
  const int wm = wid >> 1, wn = wid & 1;
  const int bm = blockIdx.x, bn = blockIdx.y;
  const int z  = (MODE == 0) ? blockIdx.z : 0;

  const bf16* Ag = A  + (long)bm * 128 * 1024;
  const bf16* Bg = Wb + (long)z * 1024 * 1024 + (long)bn * 128 * 1024;

  f32x4_t acc[4][4];
  const f32x4_t zero4 = { 0.f, 0.f, 0.f, 0.f };
  #pragma unroll
  for (int i = 0; i < 4; i++)
    #pragma unroll
    for (int j = 0; j < 4; j++) acc[i][j] = zero4;

  for (int k0 = 0; k0 < 1024; k0 += 32) {
    __syncthreads();                       // previous tile's ds_reads done
    #pragma unroll
    for (int r = 0; r < 2; r++) {
      int tt = tid + r * 256;
      int row = tt >> 2, kc = (tt & 3) * 8;
      glds16(Ag + (long)row * 1024 + k0 + kc, (void*)&As[tt * 8]);
    }
    #pragma unroll
    for (int r = 0; r < 2; r++) {
      int tt = tid + r * 256;
      int row = tt >> 2, kc = (tt & 3) * 8;
      glds16(Bg + (long)row * 1024 + k0 + kc, (void*)&Bs[tt * 8]);
    }
    __syncthreads();                       // compiler drains vmcnt before barrier

    bf16x8_t af[4], bf_[4];
    #pragma unroll
    for (int m = 0; m < 4; m++) af[m]  = *(const bf16x8_t*)&As[(wm * 64 + m * 16 + ql) * 32 + lg * 8];
    #pragma unroll
    for (int n = 0; n < 4; n++) bf_[n] = *(const bf16x8_t*)&Bs[(wn * 64 + n * 16 + ql) * 32 + lg * 8];
    #pragma unroll
    for (int m = 0; m < 4; m++)
      #pragma unroll
      for (int n = 0; n < 4; n++)
        acc[m][n] = __builtin_amdgcn_mfma_f32_16x16x32_bf16(af[m], bf_[n], acc[m][n], 0, 0, 0);
  }

  // epilogue: C/D layout col=lane&15, row=(lane>>4)*4+reg  [m89/m91]
  if (MODE == 1) {
    #pragma unroll
    for (int m = 0; m < 4; m++) {
      int rb = bm * 128 + wm * 64 + m * 16 + lg * 4;
      #pragma unroll
      for (int n = 0; n < 4; n++) {
        int colg = bn * 128 + wn * 64 + n * 16 + ql;
        float bb = bias0[colg];
        #pragma unroll
        for (int r = 0; r < 4; r++)
          dout[(long)(rb + r) * 1024 + colg] = acc[m][n][r] + bb;
      }
    }
  } else if (z == 2) {
    #pragma unroll
    for (int m = 0; m < 4; m++) {
      int rb = bm * 128 + wm * 64 + m * 16 + lg * 4;     // global token row (mult of 4)
      int bb_ = rb >> 11;                                 // batch
      int s0  = rb & 2047;                                // seq pos of reg 0
      #pragma unroll
      for (int n = 0; n < 4; n++) {
        int colg = bn * 128 + wn * 64 + n * 16 + ql;
        int h = colg >> 6, d = colg & 63;
        float bb = bias2[colg];
        // v transposed: v_t[(bh*64 + d)*2048 + s]; regs = 4 consecutive s -> 8B store
        ushort4 pkt;
        pkt.x = __builtin_bit_cast(unsigned short, (bf16)(acc[m][n][0] + bb));
        pkt.y = __builtin_bit_cast(unsigned short, (bf16)(acc[m][n][1] + bb));
        pkt.z = __builtin_bit_cast(unsigned short, (bf16)(acc[m][n][2] + bb));
        pkt.w = __builtin_bit_cast(unsigned short, (bf16)(acc[m][n][3] + bb));
        *(ushort4*)&v_t[((long)(bb_ * NHEAD + h) * 64 + d) * S_LEN + s0] = pkt;
      }
    }
  } else {
    // q or k with FUSED RoPE. For fixed (m,r) this thread holds cols d=n*16+ql (n=0..3)
    // of ONE head => pairs (n, n+2) are exactly (d, d+32) — rotate in-register.
    const float* bias = z ? bias1 : bias0;
    bf16* dst = z ? k_ws : q_ws;
    #pragma unroll
    for (int m = 0; m < 4; m++) {
      int rb = bm * 128 + wm * 64 + m * 16 + lg * 4;
      int bb_ = rb >> 11;
      int s0  = rb & 2047;
      #pragma unroll
      for (int n = 0; n < 2; n++) {
        int colg = bn * 128 + wn * 64 + n * 16 + ql;
        int h = colg >> 6, d = colg & 63;                 // d in [0,32)
        float b1 = bias[colg], b2 = bias[colg + 32];
        // inv_freq = 10000^(-d/32) = exp2(-d * log2(10000)/32)
        float inv = exp2f((float)d * -0.41524101186092026f);
        #pragma unroll
        for (int r = 0; r < 4; r++) {
          int s = s0 + r;
          float ang = (float)s * inv;
          float sn, cs;
          __sincosf(ang, &sn, &cs);
          float x1 = acc[m][n][r] + b1;
          float x2 = acc[m][n + 2][r] + b2;
          long base = ((long)(bb_ * NHEAD + h) * S_LEN + s) * 64;
          dst[base + d]      = (bf16)(x1 * cs - x2 * sn);
          dst[base + d + 32] = (bf16)(x2 * cs + x1 * sn);
        }
      }
    }
  }
}

// ---------------- flash attention: 1 wave = 32 q rows, 32x32 MFMA, KVBLK = 32 ----------------
// Swapped QK^T with mfma_f32_32x32x16: S^T = K_tile(32k x 16d) . Q^T(16d x 32q).
// C/D layout (m74/m101): col = lane&31 (=q), row crow(r,hi) = (r&3)+8*(r>>2)+4*hi (=k local).
// KEY TRICK: for PV we choose the per-lane k-mapping phi(hi,j) = 4*hi + (j&3) + 8*(j>>2)
// (bijective over 16) for BOTH the V A-operand and the P^T B-operand. Any such shared
// mapping is MFMA-correct (k-permutations cancel between A and B), and phi equals the
// crow set the lane ALREADY HOLDS from S^T -> P^T fragment = pack(pv[0..7]) with zero
// cross-lane ops. The only cross-half exchange left is the softmax max/sum pair
// reduction, done with __shfl_xor(x,32) (verified correct in rounds 2-3).
__global__ __launch_bounds__(256) void attn_kernel(const bf16* __restrict__ qw, const bf16* __restrict__ kw,
                                                   const bf16* __restrict__ vt, bf16* __restrict__ ow,
                                                   const int* __restrict__ lens)
{
  const int lane = threadIdx.x & 63, wid = threadIdx.x >> 6;
  const int lq = lane & 31, hi = lane >> 5;
  const int bh = blockIdx.y, b = bh >> 4, h = bh & 15;
  const int len = lens[b];
  // waves take q-tiles strided by 16 -> near-uniform per-block work; longest-first in x
  const int tile = (15 - (int)blockIdx.x) + wid * 16;   // 0..63
  const int q0 = tile * 32;
  const int qg = q0 + lq;

  const bf16* qh = qw + (long)bh * S_LEN * 64;
  const bf16* kh = kw + (long)bh * S_LEN * 64;
  const bf16* vh = vt + (long)bh * 64 * S_LEN;
  bf16* obase = ow + ((long)b * S_LEN + qg) * 1024 + h * 64;

  if (q0 >= len) {   // fully masked tile -> zero rows (proj then yields bo)
    ushort4 zz; zz.x = zz.y = zz.z = zz.w = 0;
    #pragma unroll
    for (int dblk = 0; dblk < 2; dblk++)
      #pragma unroll
      for (int g = 0; g < 4; g++)
        *(ushort4*)&obase[dblk * 32 + g * 8 + hi * 4] = zz;
    return;
  }

  // Q^T B-frags: lane holds q=lq col, d = ds*16 + hi*8 + j (16B contiguous loads).
  // (d-mapping assumption cancels between K and Q fragments.)
  bf16x8_t qf[4];
  #pragma unroll
  for (int ds = 0; ds < 4; ds++)
    qf[ds] = *(const bf16x8_t*)&qh[(long)qg * 64 + ds * 16 + hi * 8];

  f32x16_t o0, o1;   // O^T accum, dblk 0/1: row d = dblk*32 + crow(r,hi), col q
  #pragma unroll
  for (int r = 0; r < 16; r++) { o0[r] = 0.f; o1[r] = 0.f; }

  float m_run = -1e30f, l_run = 0.f;
  const int kend = min(q0 + 31, len - 1);

  // K prefetch: A-operand rows k = k0+lq
  bf16x8_t kf[4];
  #pragma unroll
  for (int ds = 0; ds < 4; ds++)
    kf[ds] = *(const bf16x8_t*)&kh[(long)lq * 64 + ds * 16 + hi * 8];

  for (int k0 = 0; k0 <= kend; k0 += 32) {
    // V fragments with the phi-mapping: element j <- V^T[d][k0 + ks*16 + 4*hi + (j&3) + 8*(j>>2)]
    // => two 8B loads per fragment (issued early; consumed after softmax -> latency hidden)
    u32x4_t vw[2][2];
    #pragma unroll
    for (int dblk = 0; dblk < 2; dblk++)
      #pragma unroll
      for (int ks = 0; ks < 2; ks++) {
        const bf16* vbase = &vh[(long)(dblk * 32 + lq) * S_LEN + k0 + ks * 16 + 4 * hi];
        uint2 lo8 = *(const uint2*)(vbase);
        uint2 hi8 = *(const uint2*)(vbase + 8);
        vw[dblk][ks].x = lo8.x; vw[dblk][ks].y = lo8.y;
        vw[dblk][ks].z = hi8.x; vw[dblk][ks].w = hi8.y;
      }

    // S^T = K . Q^T
    f32x16_t s;
    #pragma unroll
    for (int r = 0; r < 16; r++) s[r] = 0.f;
    #pragma unroll
    for (int ds = 0; ds < 4; ds++)
      s = __builtin_amdgcn_mfma_f32_32x32x16_bf16(kf[ds], qf[ds], s, 0, 0, 0);

    // prefetch next K tile (wave-uniform branch)
    if (k0 + 32 <= kend) {
      #pragma unroll
      for (int ds = 0; ds < 4; ds++)
        kf[ds] = *(const bf16x8_t*)&kh[(long)(k0 + 32 + lq) * 64 + ds * 16 + hi * 8];
    }

    // mask + scale (kg = k0 + crow(r,hi)), lane-local max then one pair exchange
    float pv[16];
    float mx = -1e30f;
    #pragma unroll
    for (int r = 0; r < 16; r++) {
      int kg = k0 + (r & 3) + 8 * (r >> 2) + 4 * hi;
      pv[r] = (kg <= qg && kg < len) ? s[r] * 0.125f : -1e30f;
      mx = fmaxf(mx, pv[r]);
    }
    mx = fmaxf(mx, __shfl_xor(mx, 32));
    float m_new = fmaxf(m_run, mx);
    float sc = __expf(m_run - m_new);
    float ps = 0.f;
    #pragma unroll
    for (int r = 0; r < 16; r++) { pv[r] = __expf(pv[r] - m_new); ps += pv[r]; }
    ps += __shfl_xor(ps, 32);
    l_run = l_run * sc + ps;
    m_run = m_new;
    #pragma unroll
    for (int r = 0; r < 16; r++) { o0[r] *= sc; o1[r] *= sc; }

    // P^T B-frags under phi: pf0 = pv[0..7] (k local 0..15), pf1 = pv[8..15] (16..31)
    u32x4_t f0, f1;
    f0.x = pk2(pv[0],  pv[1]);  f0.y = pk2(pv[2],  pv[3]);
    f0.z = pk2(pv[4],  pv[5]);  f0.w = pk2(pv[6],  pv[7]);
    f1.x = pk2(pv[8],  pv[9]);  f1.y = pk2(pv[10], pv[11]);
    f1.z = pk2(pv[12], pv[13]); f1.w = pk2(pv[14], pv[15]);
    bf16x8_t pf0 = __builtin_bit_cast(bf16x8_t, f0);
    bf16x8_t pf1 = __builtin_bit_cast(bf16x8_t, f1);

    // O^T += V^T . P^T  (both operands share phi -> correct for any true HW k-layout)
    o0 = __builtin_amdgcn_mfma_f32_32x32x16_bf16(__builtin_bit_cast(bf16x8_t, vw[0][0]), pf0, o0, 0, 0, 0);
    o0 = __builtin_amdgcn_mfma_f32_32x32x16_bf16(__builtin_bit_cast(bf16x8_t, vw[0][1]), pf1, o0, 0, 0, 0);
    o1 = __builtin_amdgcn_mfma_f32_32x32x16_bf16(__builtin_bit_cast(bf16x8_t, vw[1][0]), pf0, o1, 0, 0, 0);
    o1 = __builtin_amdgcn_mfma_f32_32x32x16_bf16(__builtin_bit_cast(bf16x8_t, vw[1][1]), pf1, o1, 0, 0, 0);
  }

  float rinv = (qg < len) ? (1.0f / l_run) : 0.f;  // masked rows -> exact 0
  #pragma unroll
  for (int g = 0; g < 4; g++) {
    ushort4 p0, p1;
    p0.x = __builtin_bit_cast(unsigned short, (bf16)(o0[4 * g + 0] * rinv));
    p0.y = __builtin_bit_cast(unsigned short, (bf16)(o0[4 * g + 1] * rinv));
    p0.z = __builtin_bit_cast(unsigned short, (bf16)(o0[4 * g + 2] * rinv));
    p0.w = __builtin_bit_cast(unsigned short, (bf16)(o0[4 * g + 3] * rinv));
    p1.x = __builtin_bit_cast(unsigned short, (bf16)(o1[4 * g + 0] * rinv));
    p1.y = __builtin_bit_cast(unsigned short, (bf16)(o1[4 * g + 1] * rinv));
    p1.z = __builtin_bit_cast(unsigned short, (bf16)(o1[4 * g + 2] * rinv));
    p1.w = __builtin_bit_cast(unsigned short, (bf16)(o1[4 * g + 3] * rinv));
    *(ushort4*)&obase[g * 8 + hi * 4]      = p0;
    *(ushort4*)&obase[32 + g * 8 + hi * 4] = p1;
  }
}

// ---------------- launch ----------------
extern "C" void kernel_launch(void* const* d_in, const int* in_sizes, int n_in,
                              void* d_out, int out_size, void* d_ws, size_t ws_size,
                              hipStream_t stream)
{
  const float* X  = (const float*)d_in[0];
  const float* Wq = (const float*)d_in[1];
  const float* bq = (const float*)d_in[2];
  const float* Wk = (const float*)d_in[3];
  const float* bk = (const float*)d_in[4];
  const float* Wv = (const float*)d_in[5];
  const float* bv = (const float*)d_in[6];
  const float* Wo = (const float*)d_in[7];
  const float* bo = (const float*)d_in[8];
  const int* lens = (const int*)d_in[9];
  float* out = (float*)d_out;

  char* ws = (char*)d_ws;
  bf16* x_bf = (bf16*)(ws);                         // 16 MiB: X as bf16 (8192 x 1024)
  bf16* w_bf = (bf16*)(ws + (16u << 20));           //  8 MiB: Wq,Wk,Wv,Wo bf16
  bf16* q_ws = (bf16*)(ws + (24u << 20));           // 16 MiB: (BH,S,64)
  bf16* k_ws = (bf16*)(ws + (40u << 20));           // 16 MiB: (BH,S,64)
  bf16* v_t  = (bf16*)(ws + (56u << 20));           // 16 MiB: (BH,64,S)
  bf16* o_ws = (bf16*)(ws + (72u << 20));           // 16 MiB: (B*S, 1024)

  cvt_x_kernel<<<8192, 256, 0, stream>>>((const float4*)X, (bf16x4_t*)x_bf);
  cvt_w_kernel<<<4096, 256, 0, stream>>>(Wq, Wk, Wv, Wo, (bf16x4_t*)w_bf);
  gemm_bt_kernel<0><<<dim3(64, 8, 3), 256, 0, stream>>>(x_bf, w_bf, bq, bk, bv,
                                                        q_ws, k_ws, v_t, nullptr);
  attn_kernel<<<dim3(16, 64), 256, 0, stream>>>(q_ws, k_ws, v_t, o_ws, lens);
  gemm_bt_kernel<1><<<dim3(64, 8, 1), 256, 0, stream>>>(o_ws, w_bf + 3u * 1048576u, bo, bo, bo,
                                                        q_ws, k_ws, v_t, out);
}